// Round 1
// baseline (262.818 us; speedup 1.0000x reference)
//
#include <hip/hip_runtime.h>

typedef __bf16 bf16x8 __attribute__((ext_vector_type(8)));
typedef __bf16 bf16x4 __attribute__((ext_vector_type(4)));
typedef float f32x4 __attribute__((ext_vector_type(4)));

#define EPS 1e-5f

// Precompute (re-runs every launch; d_ws is re-poisoned each time):
//   mt[s][c]  = alpha * M[c][s],  M = W_col @ W_row^T   (bf16, [32][32])
//   bwt[g][c][b] = bw[g][b][c]                          (bf16, [64][16][16])
__global__ __launch_bounds__(256) void hbsl_precompute(
    const float* __restrict__ bw, const float* __restrict__ W_row,
    const float* __restrict__ W_col, const float* __restrict__ alpha_p,
    __bf16* __restrict__ mt, __bf16* __restrict__ bwt)
{
    const int t = threadIdx.x;
    if (blockIdx.x == 0) {
        const float alpha = alpha_p[0];
        #pragma unroll
        for (int k = 0; k < 4; ++k) {
            int flat = t + 256 * k;
            int s = flat >> 5, c = flat & 31;
            float acc = 0.f;
            #pragma unroll 8
            for (int kk = 0; kk < 32; ++kk)
                acc += W_col[c * 32 + kk] * W_row[s * 32 + kk];
            mt[s * 32 + c] = (__bf16)(alpha * acc);
        }
    } else {
        int g = blockIdx.x - 1;
        int c = t >> 4, b = t & 15;
        bwt[g * 256 + c * 16 + b] = (__bf16)bw[g * 256 + b * 16 + c];
    }
}

// One block = 16 data rows. 4 waves; wave w owns out column-tiles [16w, 16w+16).
// Per out-tile o (16 cols): group g = 63-o supplies flipped block-diag part
// (flip folded into B via reversed column index), Monarch half h = o&1.
__global__ __launch_bounds__(256) void hbsl_main(
    const float* __restrict__ x, const float* __restrict__ gamma,
    const float* __restrict__ beta, const float* __restrict__ bias,
    const __bf16* __restrict__ mt, const __bf16* __restrict__ bwt,
    float* __restrict__ out)
{
    __shared__ __bf16 xn[16 * 1032];   // pitch 1032 bf16: conflict-free b128 frag reads
    const int t = threadIdx.x;
    const int lane = t & 63;
    const int wv = t >> 6;
    const int q = lane >> 4, n = lane & 15;
    const int row = t >> 4, li = t & 15;
    const int rbase = blockIdx.x * 16;

    // Monarch B-operand fragments (alpha pre-folded), held in registers.
    // B[k][s] = alpha*M[k][s] = mt[s][k]; lane: n_col = lane&15, k = q*8+j.
    bf16x8 mfrag0 = *(const bf16x8*)(mt + n * 32 + q * 8);
    bf16x8 mfrag1 = *(const bf16x8*)(mt + (16 + n) * 32 + q * 8);

    // ---- LayerNorm: 16 threads per row, 64 elems (16 float4) each ----
    const float* xr = x + (rbase + row) * 1024;
    float4 xv[16];
    float s = 0.f, ss = 0.f;
    #pragma unroll
    for (int i = 0; i < 16; ++i) {
        xv[i] = *(const float4*)(xr + li * 4 + i * 64);
        s += xv[i].x + xv[i].y + xv[i].z + xv[i].w;
        ss += xv[i].x * xv[i].x + xv[i].y * xv[i].y
            + xv[i].z * xv[i].z + xv[i].w * xv[i].w;
    }
    #pragma unroll
    for (int m = 1; m < 16; m <<= 1) {
        s  += __shfl_xor(s, m, 64);
        ss += __shfl_xor(ss, m, 64);
    }
    const float mu = s * (1.f / 1024.f);
    const float rstd = rsqrtf(ss * (1.f / 1024.f) - mu * mu + EPS);
    #pragma unroll
    for (int i = 0; i < 16; ++i) {
        const int col = li * 4 + i * 64;
        float4 g4 = *(const float4*)(gamma + col);
        float4 b4 = *(const float4*)(beta + col);
        bf16x4 v;
        v[0] = (__bf16)((xv[i].x - mu) * rstd * g4.x + b4.x);
        v[1] = (__bf16)((xv[i].y - mu) * rstd * g4.y + b4.y);
        v[2] = (__bf16)((xv[i].z - mu) * rstd * g4.z + b4.z);
        v[3] = (__bf16)((xv[i].w - mu) * rstd * g4.w + b4.w);
        *(bf16x4*)(&xn[row * 1032 + col]) = v;
    }
    __syncthreads();

    // ---- MFMA phase: 8 pairs of out-tiles per wave ----
    bf16x8 bz;
    #pragma unroll
    for (int i = 0; i < 8; ++i) bz[i] = (__bf16)0.f;
    const f32x4 zf = {0.f, 0.f, 0.f, 0.f};

    #pragma unroll
    for (int p = 0; p < 8; ++p) {
        const int o0 = wv * 16 + 2 * p;   // even out-tile; o1 = o0+1
        const int r  = o0 >> 1;           // Monarch A window (cols [32r,32r+32))
        const int gp = 31 - r;            // block-diag A window = 63-o0 pair
        const int g_odd  = 2 * gp + 1;    // group for tile o0 (k in [16,32))
        const int g_even = 2 * gp;        // group for tile o1 (k in [0,16))

        // A fragments: m = lane&15, k = q*8+j (contiguous 16B in LDS)
        bf16x8 az = *(const bf16x8*)(&xn[n * 1032 + r  * 32 + q * 8]);
        bf16x8 ay = *(const bf16x8*)(&xn[n * 1032 + gp * 32 + q * 8]);

        // block-diag B fragments, K-padded with zeros; flip folded via (15-n)
        bf16x8 by0 = bz, by1 = bz;
        if (q >= 2) by0 = *(const bf16x8*)(bwt + g_odd  * 256 + (15 - n) * 16 + (q - 2) * 8);
        else        by1 = *(const bf16x8*)(bwt + g_even * 256 + (15 - n) * 16 + q * 8);

        f32x4 z0 = __builtin_amdgcn_mfma_f32_16x16x32_bf16(az, mfrag0, zf, 0, 0, 0);
        f32x4 z1 = __builtin_amdgcn_mfma_f32_16x16x32_bf16(az, mfrag1, zf, 0, 0, 0);
        f32x4 y0 = __builtin_amdgcn_mfma_f32_16x16x32_bf16(ay, by0, zf, 0, 0, 0);
        f32x4 y1 = __builtin_amdgcn_mfma_f32_16x16x32_bf16(ay, by1, zf, 0, 0, 0);

        const float bias0 = bias[o0 * 16 + n];
        const float bias1 = bias[o0 * 16 + 16 + n];
        // D layout: col = lane&15, row = q*4 + reg
        float* op = out + (rbase + q * 4) * 1024 + o0 * 16 + n;
        #pragma unroll
        for (int rg = 0; rg < 4; ++rg) {
            op[rg * 1024]      = y0[rg] + z0[rg] + bias0;
            op[rg * 1024 + 16] = y1[rg] + z1[rg] + bias1;
        }
    }
}

extern "C" void kernel_launch(void* const* d_in, const int* in_sizes, int n_in,
                              void* d_out, int out_size, void* d_ws, size_t ws_size,
                              hipStream_t stream) {
    const float* x      = (const float*)d_in[0];
    const float* gamma  = (const float*)d_in[1];
    const float* beta   = (const float*)d_in[2];
    const float* bw     = (const float*)d_in[3];
    const float* W_row  = (const float*)d_in[4];
    const float* W_col  = (const float*)d_in[5];
    const float* alpha  = (const float*)d_in[6];
    const float* bias   = (const float*)d_in[7];
    float* o = (float*)d_out;

    __bf16* mt  = (__bf16*)d_ws;                       // 32*32*2   = 2048 B
    __bf16* bwt = (__bf16*)((char*)d_ws + 2048);       // 64*256*2  = 32768 B

    const int N = in_sizes[0] / 1024;                  // 32768 rows

    hipLaunchKernelGGL(hbsl_precompute, dim3(65), dim3(256), 0, stream,
                       bw, W_row, W_col, alpha, mt, bwt);
    hipLaunchKernelGGL(hbsl_main, dim3(N / 16), dim3(256), 0, stream,
                       x, gamma, beta, bias, mt, bwt, o);
}

// Round 2
// 258.154 us; speedup vs baseline: 1.0181x; 1.0181x over previous
//
#include <hip/hip_runtime.h>

typedef __bf16 bf16x8 __attribute__((ext_vector_type(8)));
typedef __bf16 bf16x4 __attribute__((ext_vector_type(4)));
typedef float f32x4 __attribute__((ext_vector_type(4)));

#define EPS 1e-5f

// Precompute (re-runs every launch; d_ws is re-poisoned each time):
//   mt[s][c]  = alpha * M[c][s],  M = W_col @ W_row^T   (bf16, [32][32])
//   bwt[g][c][b] = bw[g][b][c]                          (bf16, [64][16][16])
__global__ __launch_bounds__(256) void hbsl_precompute(
    const float* __restrict__ bw, const float* __restrict__ W_row,
    const float* __restrict__ W_col, const float* __restrict__ alpha_p,
    __bf16* __restrict__ mt, __bf16* __restrict__ bwt)
{
    const int t = threadIdx.x;
    if (blockIdx.x == 0) {
        const float alpha = alpha_p[0];
        #pragma unroll
        for (int k = 0; k < 4; ++k) {
            int flat = t + 256 * k;
            int s = flat >> 5, c = flat & 31;
            float acc = 0.f;
            #pragma unroll 8
            for (int kk = 0; kk < 32; ++kk)
                acc += W_col[c * 32 + kk] * W_row[s * 32 + kk];
            mt[s * 32 + c] = (__bf16)(alpha * acc);
        }
    } else {
        int g = blockIdx.x - 1;
        int c = t >> 4, b = t & 15;
        bwt[g * 256 + c * 16 + b] = (__bf16)bw[g * 256 + b * 16 + c];
    }
}

// One block = 16 data rows, 4 waves; wave wv owns out col-tiles [16wv, 16wv+16).
// MFMA operands SWAPPED vs round 1: D = W'·Xn^T, so D's col=lane&15 is the
// data row and the 4 regs are 4 CONSECUTIVE output columns -> dwordx4 stores.
__global__ __launch_bounds__(256, 4) void hbsl_main(
    const float* __restrict__ x, const float* __restrict__ gamma,
    const float* __restrict__ beta, const float* __restrict__ bias,
    const __bf16* __restrict__ mt, const __bf16* __restrict__ bwt,
    float* __restrict__ out)
{
    __shared__ __bf16 xn[16 * 1032];   // pitch 1032 bf16
    __shared__ float bias_s[1024];
    const int t = threadIdx.x;
    const int lane = t & 63;
    const int wv = t >> 6;
    const int q = lane >> 4, n = lane & 15;   // n = out-col-in-tile (A) / data row (B,D)
    const int row = t >> 4, li = t & 15;
    const int rbase = blockIdx.x * 16;

    // --- Preloads issued before the x loads (latency hidden under them) ---
    // Monarch A fragments: A'[m][k] = alpha*M[k][m(+16)] = mt[m(+16)][k]
    bf16x8 mfrag0 = *(const bf16x8*)(mt + n * 32 + q * 8);
    bf16x8 mfrag1 = *(const bf16x8*)(mt + (16 + n) * 32 + q * 8);

    // Block-diag A fragments (flip folded via 15-n). Per lane only the
    // nonzero K-half is loaded; zeros injected at use.
    bf16x8 bwf[8];
    #pragma unroll
    for (int p = 0; p < 8; ++p) {
        const int o0 = wv * 16 + 2 * p;
        const int gp = 31 - (o0 >> 1);
        const int g = (q >= 2) ? (2 * gp + 1) : (2 * gp);  // tile o0 : tile o1
        const int e = (q >= 2) ? (q - 2) * 8 : q * 8;
        bwf[p] = *(const bf16x8*)(bwt + g * 256 + (15 - n) * 16 + e);
    }

    // Stage bias in LDS (float4 per thread)
    *(float4*)(&bias_s[t * 4]) = *(const float4*)(bias + t * 4);

    // ---- LayerNorm: 16 threads per row, 64 elems (16 float4) each ----
    const float* xr = x + (size_t)(rbase + row) * 1024;
    float4 xv[16];
    float s = 0.f, ss = 0.f;
    #pragma unroll
    for (int i = 0; i < 16; ++i) {
        xv[i] = *(const float4*)(xr + li * 4 + i * 64);
        s += xv[i].x + xv[i].y + xv[i].z + xv[i].w;
        ss += xv[i].x * xv[i].x + xv[i].y * xv[i].y
            + xv[i].z * xv[i].z + xv[i].w * xv[i].w;
    }
    #pragma unroll
    for (int m = 1; m < 16; m <<= 1) {
        s  += __shfl_xor(s, m, 64);
        ss += __shfl_xor(ss, m, 64);
    }
    const float mu = s * (1.f / 1024.f);
    const float rstd = rsqrtf(ss * (1.f / 1024.f) - mu * mu + EPS);
    #pragma unroll
    for (int i = 0; i < 16; ++i) {
        const int col = li * 4 + i * 64;
        float4 g4 = *(const float4*)(gamma + col);
        float4 b4 = *(const float4*)(beta + col);
        bf16x4 v;
        v[0] = (__bf16)((xv[i].x - mu) * rstd * g4.x + b4.x);
        v[1] = (__bf16)((xv[i].y - mu) * rstd * g4.y + b4.y);
        v[2] = (__bf16)((xv[i].z - mu) * rstd * g4.z + b4.z);
        v[3] = (__bf16)((xv[i].w - mu) * rstd * g4.w + b4.w);
        *(bf16x4*)(&xn[row * 1032 + col]) = v;
    }
    __syncthreads();

    // ---- MFMA + store phase: LDS reads only, dwordx4 stores ----
    bf16x8 bz;
    #pragma unroll
    for (int i = 0; i < 8; ++i) bz[i] = (__bf16)0.f;
    const f32x4 zf = {0.f, 0.f, 0.f, 0.f};

    #pragma unroll
    for (int p = 0; p < 8; ++p) {
        const int o0 = wv * 16 + 2 * p;   // even out-tile; o1 = o0+1
        const int r  = o0 >> 1;           // Monarch window: cols [32r, 32r+32)
        const int gp = 31 - r;            // block-diag window: cols [32gp, 32gp+32)

        // B fragments (Xn^T): B[k][nrow], nrow = lane&15, k = q*8+j
        bf16x8 az = *(const bf16x8*)(&xn[n * 1032 + r  * 32 + q * 8]);
        bf16x8 ay = *(const bf16x8*)(&xn[n * 1032 + gp * 32 + q * 8]);

        // block-diag A operands, K-padded with zeros per lane half
        bf16x8 a0 = (q >= 2) ? bwf[p] : bz;   // tile o0: k in [16,32)
        bf16x8 a1 = (q <  2) ? bwf[p] : bz;   // tile o1: k in [0,16)

        f32x4 z0 = __builtin_amdgcn_mfma_f32_16x16x32_bf16(mfrag0, az, zf, 0, 0, 0);
        f32x4 z1 = __builtin_amdgcn_mfma_f32_16x16x32_bf16(mfrag1, az, zf, 0, 0, 0);
        f32x4 y0 = __builtin_amdgcn_mfma_f32_16x16x32_bf16(a0, ay, zf, 0, 0, 0);
        f32x4 y1 = __builtin_amdgcn_mfma_f32_16x16x32_bf16(a1, ay, zf, 0, 0, 0);

        f32x4 b0 = *(const f32x4*)(&bias_s[o0 * 16 + q * 4]);
        f32x4 b1 = *(const f32x4*)(&bias_s[o0 * 16 + 16 + q * 4]);

        // D: col(lane&15)=data row n, rows(q*4+rg)=4 consecutive out cols
        float* op = out + (size_t)(rbase + n) * 1024 + o0 * 16 + q * 4;
        *(f32x4*)op        = y0 + z0 + b0;
        *(f32x4*)(op + 16) = y1 + z1 + b1;
    }
}

extern "C" void kernel_launch(void* const* d_in, const int* in_sizes, int n_in,
                              void* d_out, int out_size, void* d_ws, size_t ws_size,
                              hipStream_t stream) {
    const float* x      = (const float*)d_in[0];
    const float* gamma  = (const float*)d_in[1];
    const float* beta   = (const float*)d_in[2];
    const float* bw     = (const float*)d_in[3];
    const float* W_row  = (const float*)d_in[4];
    const float* W_col  = (const float*)d_in[5];
    const float* alpha  = (const float*)d_in[6];
    const float* bias   = (const float*)d_in[7];
    float* o = (float*)d_out;

    __bf16* mt  = (__bf16*)d_ws;                       // 32*32*2   = 2048 B
    __bf16* bwt = (__bf16*)((char*)d_ws + 2048);       // 64*256*2  = 32768 B

    const int N = in_sizes[0] / 1024;                  // 32768 rows

    hipLaunchKernelGGL(hbsl_precompute, dim3(65), dim3(256), 0, stream,
                       bw, W_row, W_col, alpha, mt, bwt);
    hipLaunchKernelGGL(hbsl_main, dim3(N / 16), dim3(256), 0, stream,
                       x, gamma, beta, bias, mt, bwt, o);
}